// Round 6
// baseline (223.369 us; speedup 1.0000x reference)
//
#include <hip/hip_runtime.h>
#include <hip/hip_fp16.h>

#define BB 4096
#define NN 128
#define EPS 1e-5f

// st layout (floats): 8 shadow copies x (128 sum + 128 sumsq) per BN
#define S1 0
#define S2 2048
#define S4 4096
#define ST_FLOATS 6144
#define A4_OFF 6144   // a4: BB*NN*6 floats (12.6 MB)

static __device__ __forceinline__ float sigmoidf_(float z){
  return 1.f/(1.f+__expf(-z));
}

// fc1 (3->6) stats only. 1024 blocks x 256 threads, 2 rows/thread (262144*2 = BB*NN).
__global__ __launch_bounds__(256) void k1(const float* __restrict__ x, const float* __restrict__ w1,
                   const float* __restrict__ b1, float* __restrict__ st){
  __shared__ float bl[512];
  const int t = threadIdx.x;
  const int tid = blockIdx.x*256 + t;      // 262144 threads
  float W[18], Bv[6];
  #pragma unroll
  for (int i=0;i<18;i++) W[i]=w1[i];
  #pragma unroll
  for (int i=0;i<6;i++) Bv[i]=b1[i];
  float s=0.f, sq=0.f;
  #pragma unroll
  for (int kk=0;kk<2;kk++){
    const int r = tid + kk*262144;
    const float* xr = x + (size_t)r*3;
    float x0=xr[0], x1=xr[1], x2=xr[2];
    #pragma unroll
    for (int e=0;e<6;e++){
      float a = fmaf(x0,W[e*3+0], fmaf(x1,W[e*3+1], fmaf(x2,W[e*3+2], Bv[e])));
      s+=a; sq=fmaf(a,a,sq);
    }
  }
  bl[t]=s; bl[256+t]=sq;
  __syncthreads();
  const int shadow = (blockIdx.x & 7)*256;
  if (t<128) atomicAdd(&st[S1+shadow+t], bl[t]+bl[t+128]);
  else       atomicAdd(&st[S1+shadow+t], bl[t+128]+bl[t+256]);
}

// recompute fc1+bn1+relu, fc2 (6->12) stats only. 1024 blocks, 2 rows/thread.
__global__ __launch_bounds__(256) void k2(const float* __restrict__ x,
                   const float* __restrict__ w1, const float* __restrict__ b1,
                   const float* __restrict__ g1, const float* __restrict__ bb1,
                   const float* __restrict__ w2, const float* __restrict__ b2,
                   float* __restrict__ st){
  __shared__ float bl[512];
  const int t = threadIdx.x;
  const int tid = blockIdx.x*256 + t;
  const int n = t & 127;
  float ss=0.f, qs=0.f;
  #pragma unroll
  for (int c=0;c<8;c++){ ss+=st[S1+c*256+n]; qs+=st[S1+c*256+128+n]; }
  const float mean = ss*(1.f/(BB*6));
  const float var  = qs*(1.f/(BB*6)) - mean*mean;
  const float sc = g1[n]*rsqrtf(var+EPS), sh = bb1[n]-mean*sc;
  float W1[18], B1v[6], W2[72], B2v[12];
  #pragma unroll
  for (int i=0;i<18;i++) W1[i]=w1[i];
  #pragma unroll
  for (int i=0;i<6;i++) B1v[i]=b1[i];
  #pragma unroll
  for (int i=0;i<72;i++) W2[i]=w2[i];
  #pragma unroll
  for (int i=0;i<12;i++) B2v[i]=b2[i];
  float s=0.f, sq=0.f;
  #pragma unroll
  for (int kk=0;kk<2;kk++){
    const int r = tid + kk*262144;
    const float* xr = x + (size_t)r*3;
    float x0=xr[0], x1=xr[1], x2=xr[2];
    float h[6];
    #pragma unroll
    for (int e=0;e<6;e++){
      float a = fmaf(x0,W1[e*3+0], fmaf(x1,W1[e*3+1], fmaf(x2,W1[e*3+2], B1v[e])));
      h[e]=fmaxf(fmaf(a,sc,sh),0.f);
    }
    #pragma unroll
    for (int d=0;d<12;d++){
      float z=B2v[d];
      #pragma unroll
      for (int e=0;e<6;e++) z=fmaf(h[e],W2[d*6+e],z);
      s+=z; sq=fmaf(z,z,sq);
    }
  }
  bl[t]=s; bl[256+t]=sq;
  __syncthreads();
  const int shadow = (blockIdx.x & 7)*256;
  if (t<128) atomicAdd(&st[S2+shadow+t], bl[t]+bl[t+128]);
  else       atomicAdd(&st[S2+shadow+t], bl[t+128]+bl[t+256]);
}

// head recompute (fc1..bn2..fc3 sigmoid) + 4 relation layers + fc4 + bn4 stats.
// One wave per batch, 2 rows/lane, per-wave LDS: Us f32 6144B + Xs f16 1536B.
// No min-occupancy clamp (R3's ",4" caused 64-VGPR spills -> 35MB HBM spill traffic).
__global__ __launch_bounds__(256) void k3(
  const float* __restrict__ x,
  const float* __restrict__ w1, const float* __restrict__ b1,
  const float* __restrict__ g1, const float* __restrict__ bb1,
  const float* __restrict__ w2, const float* __restrict__ b2,
  const float* __restrict__ g2, const float* __restrict__ bb2,
  const float* __restrict__ w3, const float* __restrict__ b3,
  const float* __restrict__ u1w, const float* __restrict__ u1b,
  const float* __restrict__ ps1, const float* __restrict__ ph1, const float* __restrict__ wr1,
  const float* __restrict__ u2w, const float* __restrict__ u2b,
  const float* __restrict__ ps2, const float* __restrict__ ph2, const float* __restrict__ wr2,
  const float* __restrict__ u3w, const float* __restrict__ u3b,
  const float* __restrict__ ps3, const float* __restrict__ ph3, const float* __restrict__ wr3,
  const float* __restrict__ u4w, const float* __restrict__ u4b,
  const float* __restrict__ ps4, const float* __restrict__ ph4, const float* __restrict__ wr4,
  const float* __restrict__ w4, const float* __restrict__ b4,
  float* __restrict__ a4, float* __restrict__ st)
{
  __shared__ float lds[4][2304];
  const int wave = threadIdx.x >> 6;
  const int lane = threadIdx.x & 63;
  const int b = blockIdx.x*4 + wave;
  float* Us = &lds[wave][0];
  __half* Xs = (__half*)&lds[wave][1536];
  const int r0 = lane*2, r1 = r0+1;

  // ---- BN constants from 8-shadow sums ----
  float s1a=0,q1a=0,s1b=0,q1b=0,s2a=0,q2a=0,s2b=0,q2b=0;
  #pragma unroll
  for (int c=0;c<8;c++){
    s1a+=st[S1+c*256+r0]; q1a+=st[S1+c*256+128+r0];
    s1b+=st[S1+c*256+r1]; q1b+=st[S1+c*256+128+r1];
    s2a+=st[S2+c*256+r0]; q2a+=st[S2+c*256+128+r0];
    s2b+=st[S2+c*256+r1]; q2b+=st[S2+c*256+128+r1];
  }
  const float inv1 = 1.f/(BB*6), inv2 = 1.f/(BB*12);
  float m = s1a*inv1, v = q1a*inv1 - m*m;
  const float sA0 = g1[r0]*rsqrtf(v+EPS), hA0 = bb1[r0]-m*sA0;
  m = s1b*inv1; v = q1b*inv1 - m*m;
  const float sA1 = g1[r1]*rsqrtf(v+EPS), hA1 = bb1[r1]-m*sA1;
  m = s2a*inv2; v = q2a*inv2 - m*m;
  const float sB0 = g2[r0]*rsqrtf(v+EPS), hB0 = bb2[r0]-m*sB0;
  m = s2b*inv2; v = q2b*inv2 - m*m;
  const float sB1 = g2[r1]*rsqrtf(v+EPS), hB1 = bb2[r1]-m*sB1;

  // ---- head: fc1 + bn1 + relu + fc2 + bn2 + relu + fc3 + sigmoid ----
  const float2* xr = (const float2*)(x + ((size_t)b*128 + r0)*3);
  float2 c0=xr[0], c1=xr[1], c2=xr[2];
  const float xa0=c0.x, xa1=c0.y, xa2=c1.x;
  const float xb0=c1.y, xb1=c2.x, xb2=c2.y;

  float X0[12], X1[12];
  {
    float g6a[6], g6b[6];
    #pragma unroll
    for (int e=0;e<6;e++){
      float a0 = fmaf(xa0,w1[e*3+0], fmaf(xa1,w1[e*3+1], fmaf(xa2,w1[e*3+2], b1[e])));
      float a1v= fmaf(xb0,w1[e*3+0], fmaf(xb1,w1[e*3+1], fmaf(xb2,w1[e*3+2], b1[e])));
      g6a[e]=fmaxf(fmaf(a0,sA0,hA0),0.f);
      g6b[e]=fmaxf(fmaf(a1v,sA1,hA1),0.f);
    }
    float h0[12], h1[12];
    #pragma unroll
    for (int d=0;d<12;d++){
      float z0=b2[d], z1=b2[d];
      #pragma unroll
      for (int e=0;e<6;e++){ z0=fmaf(g6a[e],w2[d*6+e],z0); z1=fmaf(g6b[e],w2[d*6+e],z1); }
      h0[d]=fmaxf(fmaf(z0,sB0,hB0),0.f);
      h1[d]=fmaxf(fmaf(z1,sB1,hB1),0.f);
    }
    #pragma unroll
    for (int d=0; d<12; d++){
      float z0=b3[d], z1=b3[d];
      #pragma unroll
      for (int e=0;e<12;e++){ z0=fmaf(h0[e],w3[d*12+e],z0); z1=fmaf(h1[e],w3[d*12+e],z1); }
      X0[d]=sigmoidf_(z0); X1[d]=sigmoidf_(z1);
    }
  }

  const float* UW[4]  = {u1w,u2w,u3w,u4w};
  const float* UBv[4] = {u1b,u2b,u3b,u4b};
  const float cf[4] = {
    wr1[0]*ps1[0]*ph1[0]*(1.f/128.f),
    wr2[0]*ps2[0]*ph2[0]*(1.f/128.f),
    wr3[0]*ps3[0]*ph3[0]*(1.f/128.f),
    wr4[0]*ps4[0]*ph4[0]*(1.f/128.f)
  };

  const int g = lane>>4;
  int kc = lane & 15; if (kc>11) kc=11;

  #pragma unroll
  for (int l=0;l<4;l++){
    const float* uw = UW[l];
    const float* ub = UBv[l];
    float Y0[12], Y1[12];
    {
      float U0[12], U1[12];
      #pragma unroll
      for (int d=0;d<12;d++){
        float z0=ub[d], z1=ub[d];
        #pragma unroll
        for (int e=0;e<12;e++){ z0=fmaf(X0[e],uw[d*12+e],z0); z1=fmaf(X1[e],uw[d*12+e],z1); }
        U0[d]=fmaxf(z0,0.f); U1[d]=fmaxf(z1,0.f);
      }
      float q0=0.f, q1=0.f;
      #pragma unroll
      for (int e=0;e<12;e++){ q0=fmaf(X0[e],X0[e],q0); q1=fmaf(X1[e],X1[e],q1); }
      // stage U (f32) and X (f16)
      float4* uwr = (float4*)(Us + r0*12);
      uwr[0]=make_float4(U0[0],U0[1],U0[2],U0[3]);
      uwr[1]=make_float4(U0[4],U0[5],U0[6],U0[7]);
      uwr[2]=make_float4(U0[8],U0[9],U0[10],U0[11]);
      uwr[3]=make_float4(U1[0],U1[1],U1[2],U1[3]);
      uwr[4]=make_float4(U1[4],U1[5],U1[6],U1[7]);
      uwr[5]=make_float4(U1[8],U1[9],U1[10],U1[11]);
      __half2 hp[12];
      #pragma unroll
      for (int i=0;i<6;i++) hp[i]   = __floats2half2_rn(X0[2*i],X0[2*i+1]);
      #pragma unroll
      for (int i=0;i<6;i++) hp[6+i] = __floats2half2_rn(X1[2*i],X1[2*i+1]);
      {
        const uint4* hpv = (const uint4*)hp;
        uint4* xw = (uint4*)(Xs + r0*12);
        xw[0]=hpv[0]; xw[1]=hpv[1]; xw[2]=hpv[2];
      }
      // Y init = -q*U (U dies here -> lower VGPR peak)
      #pragma unroll
      for (int d=0;d<12;d++){ Y0[d] = -q0*U0[d]; Y1[d] = -q1*U1[d]; }
    }
    // wave-coherent LDS: in-order DS per wave + compiler lgkmcnt; no barrier.

    // partial M[kc][d] over this lane's 32-row chunk (rotation de-conflicts banks)
    float mp[12];
    #pragma unroll
    for (int d=0;d<12;d++) mp[d]=0.f;
    #pragma unroll
    for (int i=0;i<32;i++){
      const int n = (g<<5) + ((i+g)&31);
      const float xv = __half2float(Xs[n*12 + kc]);
      const float4* up = (const float4*)(Us + n*12);
      float4 u0=up[0], u1=up[1], u2=up[2];
      mp[0]=fmaf(xv,u0.x,mp[0]); mp[1]=fmaf(xv,u0.y,mp[1]); mp[2]=fmaf(xv,u0.z,mp[2]); mp[3]=fmaf(xv,u0.w,mp[3]);
      mp[4]=fmaf(xv,u1.x,mp[4]); mp[5]=fmaf(xv,u1.y,mp[5]); mp[6]=fmaf(xv,u1.z,mp[6]); mp[7]=fmaf(xv,u1.w,mp[7]);
      mp[8]=fmaf(xv,u2.x,mp[8]); mp[9]=fmaf(xv,u2.y,mp[9]); mp[10]=fmaf(xv,u2.z,mp[10]); mp[11]=fmaf(xv,u2.w,mp[11]);
    }
    #pragma unroll
    for (int d=0;d<12;d++) mp[d] += __shfl_xor(mp[d], 16, 64);
    #pragma unroll
    for (int d=0;d<12;d++) mp[d] += __shfl_xor(mp[d], 32, 64);

    // Y += X @ M via readlane broadcasts (M wave-uniform -> SGPR operand)
    #pragma unroll
    for (int k=0;k<12;k++){
      const float xa = X0[k], xb = X1[k];
      #pragma unroll
      for (int d=0;d<12;d++){
        const float mv = __int_as_float(__builtin_amdgcn_readlane(__float_as_int(mp[d]), k));
        Y0[d]=fmaf(xa,mv,Y0[d]); Y1[d]=fmaf(xb,mv,Y1[d]);
      }
    }
    const float coef = cf[l];
    #pragma unroll
    for (int d=0;d<12;d++){ X0[d]=coef*Y0[d]; X1[d]=coef*Y1[d]; }
  }

  // fc4 (12->6), write a4, bn4 stats (block-reduced, 8 shadow copies)
  float z0[6], z1[6];
  float s0=0.f,sq0=0.f,s1=0.f,sq1=0.f;
  #pragma unroll
  for (int e=0;e<6;e++){
    float a0=b4[e], a1v=b4[e];
    #pragma unroll
    for (int d=0;d<12;d++){ a0=fmaf(X0[d],w4[e*12+d],a0); a1v=fmaf(X1[d],w4[e*12+d],a1v); }
    z0[e]=a0; z1[e]=a1v;
    s0+=a0; sq0=fmaf(a0,a0,sq0); s1+=a1v; sq1=fmaf(a1v,a1v,sq1);
  }
  float4* aw = (float4*)(a4 + ((size_t)b*128 + r0)*6);
  aw[0]=make_float4(z0[0],z0[1],z0[2],z0[3]);
  aw[1]=make_float4(z0[4],z0[5],z1[0],z1[1]);
  aw[2]=make_float4(z1[2],z1[3],z1[4],z1[5]);

  __syncthreads();
  lds[wave][r0]=s0; lds[wave][r1]=s1;
  lds[wave][128+r0]=sq0; lds[wave][128+r1]=sq1;
  __syncthreads();
  const int t = threadIdx.x;
  const int c = (blockIdx.x & 7)*256;
  atomicAdd(&st[S4 + c + t], lds[0][t]+lds[1][t]+lds[2][t]+lds[3][t]);
}

// bn4+relu + fc5+relu + fc6/fc7 + max over N + fc8 + sigmoid.
__global__ __launch_bounds__(256) void k4(
  const float* __restrict__ a4, const float* __restrict__ g4, const float* __restrict__ bb4,
  const float* __restrict__ w5, const float* __restrict__ b5,
  const float* __restrict__ w6, const float* __restrict__ b6,
  const float* __restrict__ w7, const float* __restrict__ b7,
  const float* __restrict__ w8, const float* __restrict__ b8,
  const float* __restrict__ st, float* __restrict__ out)
{
  const int wave = threadIdx.x>>6, lane = threadIdx.x&63;
  const int b = blockIdx.x*4 + wave;
  const int r0 = lane*2, r1 = r0+1;
  float ss0=0.f, qq0=0.f, ss1=0.f, qq1=0.f;
  #pragma unroll
  for (int cc=0;cc<8;cc++){
    ss0 += st[S4+cc*256+r0];     qq0 += st[S4+cc*256+128+r0];
    ss1 += st[S4+cc*256+r1];     qq1 += st[S4+cc*256+128+r1];
  }
  const float inv = 1.f/(BB*6);
  const float mean0 = ss0*inv, var0 = qq0*inv - mean0*mean0;
  const float sc0 = g4[r0]*rsqrtf(var0+EPS), sh0 = bb4[r0]-mean0*sc0;
  const float mean1 = ss1*inv, var1 = qq1*inv - mean1*mean1;
  const float sc1 = g4[r1]*rsqrtf(var1+EPS), sh1 = bb4[r1]-mean1*sc1;

  const float4* ar = (const float4*)(a4 + ((size_t)b*128 + r0)*6);
  float4 p0=ar[0], p1=ar[1], p2=ar[2];
  float h0[6] = {p0.x,p0.y,p0.z,p0.w,p1.x,p1.y};
  float h1[6] = {p1.z,p1.w,p2.x,p2.y,p2.z,p2.w};
  #pragma unroll
  for (int e=0;e<6;e++){
    h0[e]=fmaxf(fmaf(h0[e],sc0,sh0),0.f);
    h1[e]=fmaxf(fmaf(h1[e],sc1,sh1),0.f);
  }
  float mx[3];
  {
    float h5a[3], h5b[3];
    #pragma unroll
    for (int f=0;f<3;f++){
      float za=b5[f], zb=b5[f];
      #pragma unroll
      for (int e=0;e<6;e++){ za=fmaf(h0[e],w5[f*6+e],za); zb=fmaf(h1[e],w5[f*6+e],zb); }
      h5a[f]=fmaxf(za,0.f); h5b[f]=fmaxf(zb,0.f);
    }
    float ca=b6[0], cb=b6[0];
    float g0a=b7[0], g0b=b7[0], g1a=b7[1], g1b=b7[1];
    #pragma unroll
    for (int f=0;f<3;f++){
      ca=fmaf(h5a[f],w6[f],ca);   cb=fmaf(h5b[f],w6[f],cb);
      g0a=fmaf(h5a[f],w7[f],g0a); g0b=fmaf(h5b[f],w7[f],g0b);
      g1a=fmaf(h5a[f],w7[3+f],g1a); g1b=fmaf(h5b[f],w7[3+f],g1b);
    }
    mx[0]=fmaxf(ca,cb); mx[1]=fmaxf(g0a,g0b); mx[2]=fmaxf(g1a,g1b);
  }
  #pragma unroll
  for (int off=32; off>0; off>>=1){
    mx[0]=fmaxf(mx[0], __shfl_xor(mx[0],off,64));
    mx[1]=fmaxf(mx[1], __shfl_xor(mx[1],off,64));
    mx[2]=fmaxf(mx[2], __shfl_xor(mx[2],off,64));
  }
  if (lane==0){
    float z = b8[0] + mx[0]*w8[0] + mx[1]*w8[1] + mx[2]*w8[2];
    out[b]=sigmoidf_(z);
  }
}

extern "C" void kernel_launch(void* const* d_in, const int* in_sizes, int n_in,
                              void* d_out, int out_size, void* d_ws, size_t ws_size,
                              hipStream_t stream){
  const float* x   = (const float*)d_in[0];
  const float* f1w = (const float*)d_in[1];
  const float* f1b = (const float*)d_in[2];
  const float* g1  = (const float*)d_in[3];
  const float* bb1 = (const float*)d_in[4];
  const float* f2w = (const float*)d_in[5];
  const float* f2b = (const float*)d_in[6];
  const float* g2  = (const float*)d_in[7];
  const float* bb2 = (const float*)d_in[8];
  const float* f3w = (const float*)d_in[9];
  const float* f3b = (const float*)d_in[10];
  const float* u1w = (const float*)d_in[11];
  const float* u1b = (const float*)d_in[12];
  const float* ps1 = (const float*)d_in[13];
  const float* ph1 = (const float*)d_in[14];
  const float* wr1 = (const float*)d_in[15];
  const float* u2w = (const float*)d_in[16];
  const float* u2b = (const float*)d_in[17];
  const float* ps2 = (const float*)d_in[18];
  const float* ph2 = (const float*)d_in[19];
  const float* wr2 = (const float*)d_in[20];
  const float* u3w = (const float*)d_in[21];
  const float* u3b = (const float*)d_in[22];
  const float* ps3 = (const float*)d_in[23];
  const float* ph3 = (const float*)d_in[24];
  const float* wr3 = (const float*)d_in[25];
  const float* u4w = (const float*)d_in[26];
  const float* u4b = (const float*)d_in[27];
  const float* ps4 = (const float*)d_in[28];
  const float* ph4 = (const float*)d_in[29];
  const float* wr4 = (const float*)d_in[30];
  const float* f4w = (const float*)d_in[31];
  const float* f4b = (const float*)d_in[32];
  const float* g4  = (const float*)d_in[33];
  const float* bb4 = (const float*)d_in[34];
  const float* f5w = (const float*)d_in[35];
  const float* f5b = (const float*)d_in[36];
  const float* f6w = (const float*)d_in[37];
  const float* f6b = (const float*)d_in[38];
  const float* f7w = (const float*)d_in[39];
  const float* f7b = (const float*)d_in[40];
  const float* f8w = (const float*)d_in[41];
  const float* f8b = (const float*)d_in[42];

  float* wsf = (float*)d_ws;
  float* st  = wsf;
  float* a4  = wsf + A4_OFF;
  float* out = (float*)d_out;

  hipMemsetAsync(st, 0, ST_FLOATS*sizeof(float), stream);
  k1<<<dim3(1024), dim3(256), 0, stream>>>(x, f1w, f1b, st);
  k2<<<dim3(1024), dim3(256), 0, stream>>>(x, f1w, f1b, g1, bb1, f2w, f2b, st);
  k3<<<dim3(1024), dim3(256), 0, stream>>>(x, f1w, f1b, g1, bb1, f2w, f2b, g2, bb2,
      f3w, f3b,
      u1w,u1b,ps1,ph1,wr1, u2w,u2b,ps2,ph2,wr2,
      u3w,u3b,ps3,ph3,wr3, u4w,u4b,ps4,ph4,wr4,
      f4w, f4b, a4, st);
  k4<<<dim3(1024), dim3(256), 0, stream>>>(a4, g4, bb4, f5w, f5b,
      f6w, f6b, f7w, f7b, f8w, f8b, st, out);
}